// Round 9
// baseline (315.948 us; speedup 1.0000x reference)
//
#include <hip/hip_runtime.h>
#include <hip/hip_bf16.h>

#define DEV_INLINE __device__ __forceinline__

typedef __bf16 bf16x8 __attribute__((ext_vector_type(8)));
typedef float  floatx4 __attribute__((ext_vector_type(4)));

DEV_INLINE bf16x8 ld_frag(const __bf16* p) {
    union { uint4 u; bf16x8 v; } t;
    t.u = *(const uint4*)p;
    return t.v;
}
// relu + pack two f32x4 accumulators into the next layer's B-fragment.
// Element j = relu(acc[2kq + (j>>2)][j&3]) -> matches tp_perm:
// feat(k_hw) = (2*kq + (j>>2))*16 + qd*4 + (j&3).
DEV_INLINE bf16x8 pack_relu2(floatx4 a, floatx4 b) {
    float2 p0 = {fmaxf(a[0], 0.0f), fmaxf(a[1], 0.0f)};
    float2 p1 = {fmaxf(a[2], 0.0f), fmaxf(a[3], 0.0f)};
    float2 p2 = {fmaxf(b[0], 0.0f), fmaxf(b[1], 0.0f)};
    float2 p3 = {fmaxf(b[2], 0.0f), fmaxf(b[3], 0.0f)};
    union { __hip_bfloat162 h[4]; bf16x8 v; } t;
    t.h[0] = __float22bfloat162_rn(p0);
    t.h[1] = __float22bfloat162_rn(p1);
    t.h[2] = __float22bfloat162_rn(p2);
    t.h[3] = __float22bfloat162_rn(p3);
    return t.v;
}

// ---------------------------------------------------------------------------
// Prep. tp: natural transpose+pad. tp_bias: same but bias lands in row k=Ks
// (consumed by a 1.0 in the x-fragment -> L1 bias folded into the matmul).
// tp_perm: k-permuted so consumers use prior accumulators directly as B.
// ---------------------------------------------------------------------------
template<int N, int Kp, int Ks>
DEV_INLINE void tp(__bf16* dst, const float* __restrict__ src, int idx0, int stride) {
    for (int e = idx0; e < N * Kp; e += stride) {
        int n = e / Kp, k = e - n * Kp;
        dst[e] = (k < Ks) ? (__bf16)src[k * N + n] : (__bf16)0.0f;
    }
}
template<int N, int Kp, int Ks>
DEV_INLINE void tp_bias(__bf16* dst, const float* __restrict__ src,
                        const float* __restrict__ bias, int idx0, int stride) {
    for (int e = idx0; e < N * Kp; e += stride) {
        int n = e / Kp, k = e - n * Kp;
        dst[e] = (k < Ks) ? (__bf16)src[k * N + n]
               : (k == Ks) ? (__bf16)bias[n] : (__bf16)0.0f;
    }
}
template<int N, int K>   // dst[n][k_hw] = src[c(k_hw)][n]
DEV_INLINE void tp_perm(__bf16* dst, const float* __restrict__ src, int idx0, int stride) {
    for (int e = idx0; e < N * K; e += stride) {
        int n = e / K, kh = e - n * K;
        int qd = (kh >> 3) & 3, kq = kh >> 5, j = kh & 7;
        int c = (2 * kq + (j >> 2)) * 16 + qd * 4 + (j & 3);
        dst[e] = (__bf16)src[c * N + n];
    }
}

__global__ __launch_bounds__(256)
void prep_kernel(const float* __restrict__ rw1, const float* __restrict__ rb1,
                 const float* __restrict__ rw2, const float* __restrict__ rw3,
                 const float* __restrict__ tw1, const float* __restrict__ tb1,
                 const float* __restrict__ tw2, const float* __restrict__ tw3,
                 const float* __restrict__ mw1, const float* __restrict__ mw2,
                 const float* __restrict__ mw3, __bf16* __restrict__ wb)
{
    int i0 = blockIdx.x * 256 + threadIdx.x;
    int st = gridDim.x * 256;
    tp_bias< 64,  32,   6>(wb + 0,     rw1, rb1, i0, st);
    tp_perm< 64,  64>     (wb + 2048,  rw2, i0, st);
    tp_perm< 32,  64>     (wb + 6144,  rw3, i0, st);
    tp_bias< 64,  32,   7>(wb + 8192,  tw1, tb1, i0, st);
    tp_perm< 64,  64>     (wb + 10240, tw2, i0, st);
    tp_perm< 32,  64>     (wb + 14336, tw3, i0, st);
    tp     <128, 128, 108>(wb + 16384, mw1, i0, st);
    tp_perm<128, 128>     (wb + 32768, mw2, i0, st);
    tp_perm< 64, 128>     (wb + 49152, mw3, i0, st);
}

// ---------------------------------------------------------------------------
// Encoder wave: owns whole batches (GPB groups of 32 rows), zero LDS, zero
// barriers. Weights + biases register-resident; L1 bias folded into weights;
// pooled sum/max carried in regs across groups; row-reduce via shfl_xor over
// the 4 ln bits; lanes ln==0 store 8 bf16 each. Next group's x prefetched.
// ---------------------------------------------------------------------------
template<int DIN, int S, int GPB>
DEV_INLINE void enc_wave(const float* __restrict__ X,
                         const __bf16* __restrict__ w1p,
                         const __bf16* __restrict__ w2p,
                         const __bf16* __restrict__ w3p,
                         const float* __restrict__ b2,
                         const float* __restrict__ b3,
                         __bf16* __restrict__ out,
                         int wid, int nw)
{
    constexpr int NBATCH = 16384;
    const int l64 = threadIdx.x & 63;
    const int ln  = l64 & 15;
    const int qd  = l64 >> 4;

    // ---- weights + biases -> registers, once per wave ----
    bf16x8 w1f[4], w2f[4][2], w3f[2][2];
#pragma unroll
    for (int mt = 0; mt < 4; ++mt)
        w1f[mt] = ld_frag(&w1p[(mt * 16 + ln) * 32 + qd * 8]);
#pragma unroll
    for (int mt = 0; mt < 4; ++mt)
#pragma unroll
        for (int kq = 0; kq < 2; ++kq)
            w2f[mt][kq] = ld_frag(&w2p[(mt * 16 + ln) * 64 + kq * 32 + qd * 8]);
#pragma unroll
    for (int mt = 0; mt < 2; ++mt)
#pragma unroll
        for (int kq = 0; kq < 2; ++kq)
            w3f[mt][kq] = ld_frag(&w3p[(mt * 16 + ln) * 64 + kq * 32 + qd * 8]);
    float4 bv2[4], bv3[2];
#pragma unroll
    for (int mt = 0; mt < 4; ++mt) bv2[mt] = *(const float4*)&b2[mt * 16 + qd * 4];
#pragma unroll
    for (int mt = 0; mt < 2; ++mt) bv3[mt] = *(const float4*)&b3[mt * 16 + qd * 4];

    // x loader: qd==0 lanes carry k=0..7 (x[0..DIN-1], 1.0 at k=DIN)
    auto load_x = [&](int b, int g, bf16x8 xb[2]) {
#pragma unroll
        for (int t = 0; t < 2; ++t) {
            bf16x8 v;
#pragma unroll
            for (int j = 0; j < 8; ++j) v[j] = (__bf16)0.0f;
            if (qd == 0) {
                const float* xp = X + ((size_t)b * S + (2 * g + t) * 16 + ln) * DIN;
#pragma unroll
                for (int j = 0; j < DIN; ++j) v[j] = (__bf16)xp[j];
                v[DIN] = (__bf16)1.0f;
            }
            xb[t] = v;
        }
    };

    if (wid >= NBATCH) return;
    bf16x8 xc[2];
    load_x(wid, 0, xc);

    for (int b = wid; b < NBATCH; b += nw) {
        floatx4 s[2], m[2];
#pragma unroll
        for (int mt = 0; mt < 2; ++mt) {
            s[mt] = (floatx4){0.0f, 0.0f, 0.0f, 0.0f};
            m[mt] = (floatx4){-3.4e38f, -3.4e38f, -3.4e38f, -3.4e38f};
        }
#pragma unroll
        for (int g = 0; g < GPB; ++g) {
            // ---- L1: K=32 (bias folded), acc starts at 0 ----
            floatx4 a1[2][4];
#pragma unroll
            for (int mt = 0; mt < 4; ++mt) {
                floatx4 z = (floatx4){0.0f, 0.0f, 0.0f, 0.0f};
#pragma unroll
                for (int t = 0; t < 2; ++t)
                    a1[t][mt] = __builtin_amdgcn_mfma_f32_16x16x32_bf16(w1f[mt], xc[t], z, 0, 0, 0);
            }
            // ---- prefetch next group's x (next batch g=0 after last) ----
            bf16x8 xn[2];
            {
                int nb = b, ng = g + 1;
                if (ng == GPB) { ng = 0; nb = b + nw; if (nb >= NBATCH) nb = b; }
                load_x(nb, ng, xn);
            }
            bf16x8 f1[2][2];
#pragma unroll
            for (int t = 0; t < 2; ++t)
#pragma unroll
                for (int kq = 0; kq < 2; ++kq)
                    f1[t][kq] = pack_relu2(a1[t][2 * kq], a1[t][2 * kq + 1]);

            // ---- L2: 64 -> 64 ----
            floatx4 a2[2][4];
#pragma unroll
            for (int mt = 0; mt < 4; ++mt) {
                floatx4 bi = (floatx4){bv2[mt].x, bv2[mt].y, bv2[mt].z, bv2[mt].w};
#pragma unroll
                for (int t = 0; t < 2; ++t) {
                    floatx4 acc = bi;
                    acc = __builtin_amdgcn_mfma_f32_16x16x32_bf16(w2f[mt][0], f1[t][0], acc, 0, 0, 0);
                    acc = __builtin_amdgcn_mfma_f32_16x16x32_bf16(w2f[mt][1], f1[t][1], acc, 0, 0, 0);
                    a2[t][mt] = acc;
                }
            }
            bf16x8 f2[2][2];
#pragma unroll
            for (int t = 0; t < 2; ++t)
#pragma unroll
                for (int kq = 0; kq < 2; ++kq)
                    f2[t][kq] = pack_relu2(a2[t][2 * kq], a2[t][2 * kq + 1]);

            // ---- L3: 64 -> 32, combine into pooled regs ----
#pragma unroll
            for (int mt = 0; mt < 2; ++mt) {
                floatx4 bi = (floatx4){bv3[mt].x, bv3[mt].y, bv3[mt].z, bv3[mt].w};
#pragma unroll
                for (int t = 0; t < 2; ++t) {
                    floatx4 acc = bi;
                    acc = __builtin_amdgcn_mfma_f32_16x16x32_bf16(w3f[mt][0], f2[t][0], acc, 0, 0, 0);
                    acc = __builtin_amdgcn_mfma_f32_16x16x32_bf16(w3f[mt][1], f2[t][1], acc, 0, 0, 0);
                    s[mt] = s[mt] + acc;
#pragma unroll
                    for (int j = 0; j < 4; ++j) m[mt][j] = fmaxf(m[mt][j], acc[j]);
                }
            }
            xc[0] = xn[0]; xc[1] = xn[1];
        }
        // ---- row-reduce across ln lanes (rows live in lanes) ----
#pragma unroll
        for (int d = 1; d < 16; d <<= 1) {
#pragma unroll
            for (int mt = 0; mt < 2; ++mt)
#pragma unroll
                for (int j = 0; j < 4; ++j) {
                    s[mt][j] += __shfl_xor(s[mt][j], d, 64);
                    float o = __shfl_xor(m[mt][j], d, 64);
                    m[mt][j] = fmaxf(m[mt][j], o);
                }
        }
        if (ln == 0) {
            constexpr float invS = 1.0f / (float)S;
#pragma unroll
            for (int mt = 0; mt < 2; ++mt) {
                union { __bf16 h[4]; uint2 u; } o;
#pragma unroll
                for (int j = 0; j < 4; ++j)
                    o.h[j] = (__bf16)(0.5f * (s[mt][j] * invS + m[mt][j]));
                *(uint2*)&out[(size_t)b * 32 + mt * 16 + qd * 4] = o.u;
            }
        }
    }
}

#define NRB 341
#define NTB 683

__global__ __launch_bounds__(256)
void enc_fused(const float* __restrict__ rX, const float* __restrict__ tX,
               const __bf16* __restrict__ wb,
               const float* __restrict__ rb2, const float* __restrict__ rb3,
               const float* __restrict__ tb2, const float* __restrict__ tb3,
               __bf16* __restrict__ remb, __bf16* __restrict__ temb)
{
    const int w = threadIdx.x >> 6;
    if ((int)blockIdx.x < NRB) {
        int wid = blockIdx.x * 4 + w;
        enc_wave<6, 64, 2>(rX, wb, wb + 2048, wb + 6144,
                           rb2, rb3, remb, wid, NRB * 4);
    } else {
        int wid = (blockIdx.x - NRB) * 4 + w;
        enc_wave<7, 128, 4>(tX, wb + 8192, wb + 10240, wb + 14336,
                            tb2, tb3, temb, wid, NTB * 4);
    }
}

// ---------------------------------------------------------------------------
// Head, register-chained (R7/R8): stage c (1 barrier), then L1->L2->L3->dot
// in regs per wave (16 rows each). hw2/hw3 k-permuted; hw1/b*/w4 natural.
// ---------------------------------------------------------------------------
__global__ __launch_bounds__(256)
void head_mfma(const float* __restrict__ t0,
               const __bf16* __restrict__ remb, const __bf16* __restrict__ temb,
               const __bf16* __restrict__ hw1, const float* __restrict__ b1,
               const __bf16* __restrict__ hw2, const float* __restrict__ b2,
               const __bf16* __restrict__ hw3, const float* __restrict__ b3,
               const float* __restrict__ w4, const float* __restrict__ b4,
               float* __restrict__ out)
{
    __shared__ __align__(16) __bf16 cb[64 * 136];

    const int tid = threadIdx.x;
    const int w   = tid >> 6;
    const int l64 = tid & 63;
    const int ln  = l64 & 15;
    const int qd  = l64 >> 4;
    const int g0  = blockIdx.x * 64;

    for (int i = tid; i < 64 * 44; i += 256) {
        int r = i / 44, k = i - r * 44;
        cb[r * 136 + k] = (__bf16)t0[(size_t)(g0 + r) * 44 + k];
    }
    for (int i = tid; i < 64 * 32; i += 256) {
        int r = i >> 5, k = i & 31;
        cb[r * 136 + 44 + k] = remb[(size_t)(g0 + r) * 32 + k];
        cb[r * 136 + 76 + k] = temb[(size_t)(g0 + r) * 32 + k];
    }
    for (int i = tid; i < 64 * 20; i += 256) {
        int r = i / 20, k = i - r * 20;
        cb[r * 136 + 108 + k] = (__bf16)0.0f;
    }
    __syncthreads();

    bf16x8 cf[4];
#pragma unroll
    for (int kq = 0; kq < 4; ++kq)
        cf[kq] = ld_frag(&cb[(w * 16 + ln) * 136 + kq * 32 + qd * 8]);
    floatx4 acc1[8];
#pragma unroll
    for (int mt = 0; mt < 8; ++mt) {
        float4 bv = *(const float4*)&b1[mt * 16 + qd * 4];
        floatx4 acc = (floatx4){bv.x, bv.y, bv.z, bv.w};
#pragma unroll
        for (int kq = 0; kq < 4; ++kq) {
            bf16x8 af = ld_frag(&hw1[(mt * 16 + ln) * 128 + kq * 32 + qd * 8]);
            acc = __builtin_amdgcn_mfma_f32_16x16x32_bf16(af, cf[kq], acc, 0, 0, 0);
        }
        acc1[mt] = acc;
    }
    bf16x8 f1[4];
#pragma unroll
    for (int kq = 0; kq < 4; ++kq)
        f1[kq] = pack_relu2(acc1[2 * kq], acc1[2 * kq + 1]);

    floatx4 acc2[8];
#pragma unroll
    for (int mt = 0; mt < 8; ++mt) {
        float4 bv = *(const float4*)&b2[mt * 16 + qd * 4];
        floatx4 acc = (floatx4){bv.x, bv.y, bv.z, bv.w};
#pragma unroll
        for (int kq = 0; kq < 4; ++kq) {
            bf16x8 af = ld_frag(&hw2[(mt * 16 + ln) * 128 + kq * 32 + qd * 8]);
            acc = __builtin_amdgcn_mfma_f32_16x16x32_bf16(af, f1[kq], acc, 0, 0, 0);
        }
        acc2[mt] = acc;
    }
    bf16x8 f2[4];
#pragma unroll
    for (int kq = 0; kq < 4; ++kq)
        f2[kq] = pack_relu2(acc2[2 * kq], acc2[2 * kq + 1]);

    floatx4 acc3[4];
#pragma unroll
    for (int mt = 0; mt < 4; ++mt) {
        float4 bv = *(const float4*)&b3[mt * 16 + qd * 4];
        floatx4 acc = (floatx4){bv.x, bv.y, bv.z, bv.w};
#pragma unroll
        for (int kq = 0; kq < 4; ++kq) {
            bf16x8 af = ld_frag(&hw3[(mt * 16 + ln) * 128 + kq * 32 + qd * 8]);
            acc = __builtin_amdgcn_mfma_f32_16x16x32_bf16(af, f2[kq], acc, 0, 0, 0);
        }
        acc3[mt] = acc;
    }

    float part = 0.0f;
#pragma unroll
    for (int mt = 0; mt < 4; ++mt) {
        float4 wv = *(const float4*)&w4[mt * 16 + qd * 4];
        part = fmaf(fmaxf(acc3[mt][0], 0.0f), wv.x, part);
        part = fmaf(fmaxf(acc3[mt][1], 0.0f), wv.y, part);
        part = fmaf(fmaxf(acc3[mt][2], 0.0f), wv.z, part);
        part = fmaf(fmaxf(acc3[mt][3], 0.0f), wv.w, part);
    }
    part += __shfl_xor(part, 16);
    part += __shfl_xor(part, 32);
    if (qd == 0)
        out[g0 + w * 16 + ln] = part + b4[0];
}

extern "C" void kernel_launch(void* const* d_in, const int* in_sizes, int n_in,
                              void* d_out, int out_size, void* d_ws, size_t ws_size,
                              hipStream_t stream)
{
    const float* t0  = (const float*)d_in[0];
    const float* rX  = (const float*)d_in[1];
    const float* tX  = (const float*)d_in[2];
    const float* rw1 = (const float*)d_in[3];  const float* rb1 = (const float*)d_in[4];
    const float* rw2 = (const float*)d_in[5];  const float* rb2 = (const float*)d_in[6];
    const float* rw3 = (const float*)d_in[7];  const float* rb3 = (const float*)d_in[8];
    const float* tw1 = (const float*)d_in[9];  const float* tb1 = (const float*)d_in[10];
    const float* tw2 = (const float*)d_in[11]; const float* tb2 = (const float*)d_in[12];
    const float* tw3 = (const float*)d_in[13]; const float* tb3 = (const float*)d_in[14];
    const float* mw1 = (const float*)d_in[15]; const float* mb1 = (const float*)d_in[16];
    const float* mw2 = (const float*)d_in[17]; const float* mb2 = (const float*)d_in[18];
    const float* mw3 = (const float*)d_in[19]; const float* mb3 = (const float*)d_in[20];
    const float* mw4 = (const float*)d_in[21]; const float* mb4 = (const float*)d_in[22];
    float* out = (float*)d_out;

    const int B = 16384;
    __bf16* remb = (__bf16*)d_ws;
    __bf16* temb = (__bf16*)((char*)d_ws + ((size_t)1 << 20));
    __bf16* wb   = (__bf16*)((char*)d_ws + ((size_t)2 << 20));
    const __bf16* mw1b = wb + 16384; const __bf16* mw2b = wb + 32768;
    const __bf16* mw3b = wb + 49152;

    prep_kernel<<<64, 256, 0, stream>>>(rw1, rb1, rw2, rw3, tw1, tb1, tw2, tw3,
                                        mw1, mw2, mw3, wb);
    enc_fused<<<NRB + NTB, 256, 0, stream>>>(rX, tX, wb,
                                             rb2, rb3, tb2, tb3, remb, temb);
    head_mfma<<<B / 64, 256, 0, stream>>>(t0, remb, temb,
                                          mw1b, mb1, mw2b, mb2, mw3b, mb3,
                                          mw4, mb4, out);
}